// Round 10
// baseline (71.171 us; speedup 1.0000x reference)
//
#include <hip/hip_runtime.h>

// SSIM loss: predict/gt (32,1,512,512) f32, 11-tap separable gaussian (sigma=1.5),
// VALID padding -> 502x502 per image, loss = 1 - mean(ssim_map).
//
// Round 10: both convolutions on MFMA (banded-weight matmul).
//   vertical:  D = A_wgt(16x32, A[i][k]=W[k-i]) x B_data(32x16)   per ch/colgroup
//   horizontal:D = A_data(16x32) x B_wgt(32x16, B[k][j]=W[k-j])   per ch/outgroup
// One weight fragment serves both. Data staged f16 col-major (XOR-swizzled
// k-blocks, conflict-free), V intermediate f16 row-major (pitch 132).
// SSIM epilogue in f32 on D fragments. Block = 16 out rows x 112 out cols.

typedef _Float16 f16;
typedef __attribute__((ext_vector_type(4))) _Float16 f16x4;
typedef __attribute__((ext_vector_type(8))) _Float16 f16x8;
typedef __attribute__((ext_vector_type(4))) float f32x4;

constexpr int WIN = 11;
constexpr int H = 512, W = 512, NIMG = 32;
constexpr int OH = H - WIN + 1, OW = W - WIN + 1;  // 502
constexpr int OR_ = 16;      // output rows per block
constexpr int OC = 112;      // output cols per block (7 groups of 16)
constexpr int SC = 128;      // staged cols (8 groups of 16)
constexpr int KP = 32;       // k slots per staged col
constexpr int VP = 132;      // V buffer col pitch (33 8B-pairs -> conflict-free A reads)
constexpr int NSTRIP = 32;   // ceil(502/16)
constexpr int NCB = 5;       // ceil(502/112)
constexpr int NBLK = NIMG * NSTRIP * NCB;  // 5120
constexpr float C1 = 0.009801f;   // (0.01*9.9)^2
constexpr float C2 = 0.088209f;   // (0.03*9.9)^2
constexpr double TOTAL = (double)NIMG * (double)OH * (double)OW;

__device__ constexpr float WGT[WIN] = {
    0.0010285f, 0.0075988f, 0.0360008f, 0.1093607f, 0.2130054f,
    0.2660118f,
    0.2130054f, 0.1093607f, 0.0360008f, 0.0075988f, 0.0010285f};

__global__ __launch_bounds__(256, 2) void ssim_mfma_kernel(const float* __restrict__ P,
                                                           const float* __restrict__ G,
                                                           float* __restrict__ blocksum) {
    __shared__ f16 SB[5][SC][KP];    // staged channels, col-major k   (40960 B)
    __shared__ f16 VB[5][OR_][VP];   // vertically blurred, row-major  (21120 B)
    __shared__ float wsum[4];

    const int tid = threadIdx.x;
    const int lane = tid & 63;
    const int wid = tid >> 6;
    const int r = lane & 15;         // A row / B col / D col
    const int q = lane >> 4;         // k-group; D rows 4q..4q+3

    const int bid = blockIdx.x;
    const int img = bid / (NSTRIP * NCB);
    const int rem = bid % (NSTRIP * NCB);
    const int strip = rem / NCB;
    const int cb = rem % NCB;
    const int R0 = strip * OR_;
    const int C0 = cb * OC;

    // weight fragment: elem e -> logical k; value = W[k - r] banded (0 outside).
    // Same frag is A for vertical (i=r) and B for horizontal (j=r).
    f16x8 wfrag;
#pragma unroll
    for (int e = 0; e < 8; ++e) {
        const int k = (e < 4) ? (4 * q + e) : (16 + 4 * q + (e - 4));
        const int d = k - r;
        wfrag[e] = (d >= 0 && d <= 10) ? (f16)WGT[d] : (f16)0.f;
    }

    const float* p = P + (size_t)img * H * W;
    const float* g = G + (size_t)img * H * W;

    // ---- stage: rows R0..R0+27 (k=0..27, 7 quads) x 128 cols, col-major,
    // k-block b stored at (b ^ (col&7)) for bank spread.
    for (int t = tid; t < 7 * SC; t += 256) {
        const int quad = t >> 7;
        const int col = t & 127;
        const int gc = min(C0 + col, W - 1);
        float pv[4], gv[4];
#pragma unroll
        for (int i = 0; i < 4; ++i) {
            const int gr = min(R0 + 4 * quad + i, H - 1);
            pv[i] = p[gr * W + gc];
            gv[i] = g[gr * W + gc];
        }
        f16x4 c0, c1, c2, c3, c4;
#pragma unroll
        for (int i = 0; i < 4; ++i) {
            c0[i] = (f16)pv[i];
            c1[i] = (f16)gv[i];
            c2[i] = (f16)(pv[i] * pv[i]);
            c3[i] = (f16)(gv[i] * gv[i]);
            c4[i] = (f16)(pv[i] * gv[i]);
        }
        const int eoff = ((quad ^ (col & 7)) << 2);
        *(f16x4*)&SB[0][col][eoff] = c0;
        *(f16x4*)&SB[1][col][eoff] = c1;
        *(f16x4*)&SB[2][col][eoff] = c2;
        *(f16x4*)&SB[3][col][eoff] = c3;
        *(f16x4*)&SB[4][col][eoff] = c4;
    }
    // zero logical k-block 7 (k=28..31; weights are 0 there but data must be finite)
    {
        const f16x4 z4 = {(f16)0.f, (f16)0.f, (f16)0.f, (f16)0.f};
        for (int t = tid; t < 5 * SC; t += 256) {
            const int ch = t >> 7;
            const int col = t & 127;
            *(f16x4*)&SB[ch][col][((7 ^ (col & 7)) << 2)] = z4;
        }
    }
    __syncthreads();

    const f32x4 zero = {0.f, 0.f, 0.f, 0.f};

    // ---- vertical MFMA: 5 ch x 8 colgroups = 40 tiles, 10 per wave
    for (int t = wid; t < 40; t += 4) {
        const int ch = t >> 3;
        const int cg = t & 7;
        const int col = cg * 16 + r;
        const int c7 = col & 7;
        const f16x4 d0 = *(const f16x4*)&SB[ch][col][((q ^ c7) << 2)];         // k 4q..4q+3
        const f16x4 d1 = *(const f16x4*)&SB[ch][col][(((4 + q) ^ c7) << 2)];   // k 16+4q..
        const f16x8 bfrag = __builtin_shufflevector(d0, d1, 0, 1, 2, 3, 4, 5, 6, 7);
        const f32x4 D = __builtin_amdgcn_mfma_f32_16x16x32_f16(wfrag, bfrag, zero, 0, 0, 0);
#pragma unroll
        for (int m = 0; m < 4; ++m)
            VB[ch][4 * q + m][col] = (f16)D[m];   // D: row=4q+m, col=r (+16cg)
    }
    __syncthreads();

    // ---- horizontal MFMA + SSIM: 7 outgroups x 5 ch
    float lsum = 0.f;
    for (int og = wid; og < 7; og += 4) {
        f32x4 acc[5];
#pragma unroll
        for (int ch = 0; ch < 5; ++ch) {
            const f16* vp_ = &VB[ch][r][og * 16 + q * 4];
            const f16x4 a0 = *(const f16x4*)vp_;           // V cols 16og+4q..+3
            const f16x4 a1 = *(const f16x4*)(vp_ + 16);    // V cols 16og+16+4q..
            const f16x8 afrag = __builtin_shufflevector(a0, a1, 0, 1, 2, 3, 4, 5, 6, 7);
            acc[ch] = __builtin_amdgcn_mfma_f32_16x16x32_f16(afrag, wfrag, zero, 0, 0, 0);
        }
        const int ocol = C0 + og * 16 + r;
#pragma unroll
        for (int m = 0; m < 4; ++m) {
            const int orow = R0 + 4 * q + m;
            const bool ok = (orow < OH) && (ocol < OW);
            const float m1 = acc[0][m], m2 = acc[1][m];
            const float e11 = acc[2][m], e22 = acc[3][m], e12 = acc[4][m];
            const float mu11 = m1 * m1, mu22 = m2 * m2, mu12 = m1 * m2;
            const float s11 = e11 - mu11, s22 = e22 - mu22, s12 = e12 - mu12;
            const float num = (2.f * mu12 + C1) * (2.f * s12 + C2);
            const float den = (mu11 + mu22 + C1) * (s11 + s22 + C2);
            lsum += ok ? __fdividef(num, den) : 0.f;
        }
    }

    // ---- block reduction
#pragma unroll
    for (int off = 32; off > 0; off >>= 1)
        lsum += __shfl_down(lsum, off, 64);
    if (lane == 0) wsum[wid] = lsum;
    __syncthreads();
    if (tid == 0)
        blocksum[bid] = (wsum[0] + wsum[1]) + (wsum[2] + wsum[3]);
}

// one-block reduction of 5120 block sums -> loss scalar
__global__ __launch_bounds__(256) void reduce_kernel(const float* __restrict__ blocksum,
                                                     float* __restrict__ out, int n) {
    const int tid = threadIdx.x;
    float s = 0.f;
    for (int i = tid; i < n; i += 256) s += blocksum[i];
#pragma unroll
    for (int off = 32; off > 0; off >>= 1)
        s += __shfl_down(s, off, 64);
    __shared__ float wsum[4];
    const int wid = tid >> 6, lane = tid & 63;
    if (lane == 0) wsum[wid] = s;
    __syncthreads();
    if (tid == 0) {
        const float total = (wsum[0] + wsum[1]) + (wsum[2] + wsum[3]);
        out[0] = 1.f - total * (float)(1.0 / TOTAL);
    }
}

extern "C" void kernel_launch(void* const* d_in, const int* in_sizes, int n_in,
                              void* d_out, int out_size, void* d_ws, size_t ws_size,
                              hipStream_t stream) {
    const float* P = (const float*)d_in[0];   // predict
    const float* G = (const float*)d_in[1];   // gt
    float* out = (float*)d_out;
    float* blocksum = (float*)d_ws;           // NBLK floats

    ssim_mfma_kernel<<<NBLK, 256, 0, stream>>>(P, G, blocksum);
    reduce_kernel<<<1, 256, 0, stream>>>(blocksum, out, NBLK);
}

// Round 11
// 47.408 us; speedup vs baseline: 1.5012x; 1.5012x over previous
//
#include <hip/hip_runtime.h>

// SSIM loss: predict/gt (32,1,512,512) f32, 11-tap separable gaussian (sigma=1.5),
// VALID padding -> 502x502 per image, loss = 1 - mean(ssim_map).
//
// Round 11: MFMA conv (verified r10 mapping) + residency fixes.
//  - stage only p,g in f16 (products computed in registers via v_pk_mul_f16)
//  - SB k-pitch 36 f16 (72B): 9r mod 16 bijective -> conflict-free writes+reads
//  - LDS 39.6KB -> 4 blocks/CU (was 62.5KB -> 2)
// vertical:  D = A_wgt(16x32 banded) x B_data(32x16)  ; horizontal: D = A_data x B_wgt.

typedef _Float16 f16;
typedef __attribute__((ext_vector_type(4))) _Float16 f16x4;
typedef __attribute__((ext_vector_type(8))) _Float16 f16x8;
typedef __attribute__((ext_vector_type(4))) float f32x4;

constexpr int WIN = 11;
constexpr int H = 512, W = 512, NIMG = 32;
constexpr int OH = H - WIN + 1, OW = W - WIN + 1;  // 502
constexpr int OR_ = 16;      // output rows per block
constexpr int OC = 112;      // output cols per block (7 groups of 16)
constexpr int SC = 128;      // staged cols (8 groups of 16)
constexpr int KP = 36;       // SB k-pitch in f16 (72B row: conflict-free)
constexpr int VP = 132;      // V buffer col pitch (264B: conflict-free)
constexpr int NSTRIP = 32;   // ceil(502/16)
constexpr int NCB = 5;       // ceil(502/112)
constexpr int NBLK = NIMG * NSTRIP * NCB;  // 5120
constexpr float C1 = 0.009801f;   // (0.01*9.9)^2
constexpr float C2 = 0.088209f;   // (0.03*9.9)^2
constexpr double TOTAL = (double)NIMG * (double)OH * (double)OW;

__device__ constexpr float WGT[WIN] = {
    0.0010285f, 0.0075988f, 0.0360008f, 0.1093607f, 0.2130054f,
    0.2660118f,
    0.2130054f, 0.1093607f, 0.0360008f, 0.0075988f, 0.0010285f};

__global__ __launch_bounds__(256, 4) void ssim_mfma_kernel(const float* __restrict__ P,
                                                           const float* __restrict__ G,
                                                           float* __restrict__ blocksum) {
    __shared__ f16 SB[2][SC][KP];    // staged p,g col-major in k     (18432 B)
    __shared__ f16 VB[5][OR_][VP];   // vertically blurred, row-major (21120 B)
    __shared__ float wsum[4];

    const int tid = threadIdx.x;
    const int lane = tid & 63;
    const int wid = tid >> 6;
    const int r = lane & 15;         // A row / B col / D col
    const int q = lane >> 4;         // k-group; D rows 4q..4q+3

    const int bid = blockIdx.x;
    const int img = bid / (NSTRIP * NCB);
    const int rem = bid % (NSTRIP * NCB);
    const int strip = rem / NCB;
    const int cb = rem % NCB;
    const int R0 = strip * OR_;
    const int C0 = cb * OC;

    // weight fragment: elem e -> k; value = W[k - r] banded (0 outside).
    // Serves as A for vertical (i=r) and B for horizontal (j=r).  [verified r10]
    f16x8 wfrag;
#pragma unroll
    for (int e = 0; e < 8; ++e) {
        const int k = (e < 4) ? (4 * q + e) : (16 + 4 * q + (e - 4));
        const int d = k - r;
        wfrag[e] = (d >= 0 && d <= 10) ? (f16)WGT[d] : (f16)0.f;
    }

    const float* p = P + (size_t)img * H * W;
    const float* g = G + (size_t)img * H * W;

    // ---- stage rows R0..R0+27 (k 0..27) + zero k 28..31; 8 quads x 128 cols
    for (int t = tid; t < 8 * SC; t += 256) {
        const int quad = t >> 7;       // wave-uniform
        const int col = t & 127;
        if (quad < 7) {
            const int gc = min(C0 + col, W - 1);
            f16x4 cp, cg_;
#pragma unroll
            for (int i = 0; i < 4; ++i) {
                const int gr = min(R0 + 4 * quad + i, H - 1);
                cp[i] = (f16)p[gr * W + gc];
                cg_[i] = (f16)g[gr * W + gc];
            }
            *(f16x4*)&SB[0][col][4 * quad] = cp;
            *(f16x4*)&SB[1][col][4 * quad] = cg_;
        } else {
            const f16x4 z4 = {(f16)0.f, (f16)0.f, (f16)0.f, (f16)0.f};
            *(f16x4*)&SB[0][col][28] = z4;
            *(f16x4*)&SB[1][col][28] = z4;
        }
    }
    __syncthreads();

    const f32x4 zero = {0.f, 0.f, 0.f, 0.f};

    // ---- vertical MFMA: 8 colgroups, 2 per wave; products built in registers
    for (int t = wid; t < 8; t += 4) {
        const int col = t * 16 + r;
        const f16* sb0 = &SB[0][col][0];
        const f16* sb1 = &SB[1][col][0];
        const f16x4 p0 = *(const f16x4*)(sb0 + 4 * q);
        const f16x4 p1 = *(const f16x4*)(sb0 + 16 + 4 * q);
        const f16x4 g0 = *(const f16x4*)(sb1 + 4 * q);
        const f16x4 g1 = *(const f16x4*)(sb1 + 16 + 4 * q);
        const f16x8 bp = __builtin_shufflevector(p0, p1, 0, 1, 2, 3, 4, 5, 6, 7);
        const f16x8 bg = __builtin_shufflevector(g0, g1, 0, 1, 2, 3, 4, 5, 6, 7);
        const f16x8 bpp = bp * bp;
        const f16x8 bgg = bg * bg;
        const f16x8 bpg = bp * bg;
        const f32x4 D0 = __builtin_amdgcn_mfma_f32_16x16x32_f16(wfrag, bp,  zero, 0, 0, 0);
        const f32x4 D1 = __builtin_amdgcn_mfma_f32_16x16x32_f16(wfrag, bg,  zero, 0, 0, 0);
        const f32x4 D2 = __builtin_amdgcn_mfma_f32_16x16x32_f16(wfrag, bpp, zero, 0, 0, 0);
        const f32x4 D3 = __builtin_amdgcn_mfma_f32_16x16x32_f16(wfrag, bgg, zero, 0, 0, 0);
        const f32x4 D4 = __builtin_amdgcn_mfma_f32_16x16x32_f16(wfrag, bpg, zero, 0, 0, 0);
#pragma unroll
        for (int m = 0; m < 4; ++m) {
            const int row = 4 * q + m;
            VB[0][row][col] = (f16)D0[m];
            VB[1][row][col] = (f16)D1[m];
            VB[2][row][col] = (f16)D2[m];
            VB[3][row][col] = (f16)D3[m];
            VB[4][row][col] = (f16)D4[m];
        }
    }
    __syncthreads();

    // ---- horizontal MFMA + SSIM: 7 outgroups across 4 waves
    float lsum = 0.f;
    for (int og = wid; og < 7; og += 4) {
        f32x4 acc[5];
#pragma unroll
        for (int ch = 0; ch < 5; ++ch) {
            const f16* vp_ = &VB[ch][r][og * 16 + q * 4];
            const f16x4 a0 = *(const f16x4*)vp_;           // V cols 16og+4q..+3
            const f16x4 a1 = *(const f16x4*)(vp_ + 16);    // V cols 16og+16+4q..
            const f16x8 afrag = __builtin_shufflevector(a0, a1, 0, 1, 2, 3, 4, 5, 6, 7);
            acc[ch] = __builtin_amdgcn_mfma_f32_16x16x32_f16(afrag, wfrag, zero, 0, 0, 0);
        }
        const int ocol = C0 + og * 16 + r;
#pragma unroll
        for (int m = 0; m < 4; ++m) {
            const int orow = R0 + 4 * q + m;
            const bool ok = (orow < OH) && (ocol < OW);
            const float m1 = acc[0][m], m2 = acc[1][m];
            const float e11 = acc[2][m], e22 = acc[3][m], e12 = acc[4][m];
            const float mu11 = m1 * m1, mu22 = m2 * m2, mu12 = m1 * m2;
            const float s11 = e11 - mu11, s22 = e22 - mu22, s12 = e12 - mu12;
            const float num = (2.f * mu12 + C1) * (2.f * s12 + C2);
            const float den = (mu11 + mu22 + C1) * (s11 + s22 + C2);
            lsum += ok ? __fdividef(num, den) : 0.f;
        }
    }

    // ---- block reduction
#pragma unroll
    for (int off = 32; off > 0; off >>= 1)
        lsum += __shfl_down(lsum, off, 64);
    if (lane == 0) wsum[wid] = lsum;
    __syncthreads();
    if (tid == 0)
        blocksum[bid] = (wsum[0] + wsum[1]) + (wsum[2] + wsum[3]);
}

// one-block reduction of 5120 block sums -> loss scalar
__global__ __launch_bounds__(256) void reduce_kernel(const float* __restrict__ blocksum,
                                                     float* __restrict__ out, int n) {
    const int tid = threadIdx.x;
    float s = 0.f;
    for (int i = tid; i < n; i += 256) s += blocksum[i];
#pragma unroll
    for (int off = 32; off > 0; off >>= 1)
        s += __shfl_down(s, off, 64);
    __shared__ float wsum[4];
    const int wid = tid >> 6, lane = tid & 63;
    if (lane == 0) wsum[wid] = s;
    __syncthreads();
    if (tid == 0) {
        const float total = (wsum[0] + wsum[1]) + (wsum[2] + wsum[3]);
        out[0] = 1.f - total * (float)(1.0 / TOTAL);
    }
}

extern "C" void kernel_launch(void* const* d_in, const int* in_sizes, int n_in,
                              void* d_out, int out_size, void* d_ws, size_t ws_size,
                              hipStream_t stream) {
    const float* P = (const float*)d_in[0];   // predict
    const float* G = (const float*)d_in[1];   // gt
    float* out = (float*)d_out;
    float* blocksum = (float*)d_ws;           // NBLK floats

    ssim_mfma_kernel<<<NBLK, 256, 0, stream>>>(P, G, blocksum);
    reduce_kernel<<<1, 256, 0, stream>>>(blocksum, out, NBLK);
}

// Round 12
// 43.553 us; speedup vs baseline: 1.6341x; 1.0885x over previous
//
#include <hip/hip_runtime.h>

// SSIM loss: predict/gt (32,1,512,512) f32, 11-tap separable gaussian (sigma=1.5),
// VALID padding -> 502x502 per image, loss = 1 - mean(ssim_map).
//
// Round 12: MFMA conv with V kept in registers (no LDS transpose, 1 barrier).
//   vertical:   D = A_data(16x32, A[c][k]=X[row k][col c]) x B_wgt(banded)
//               -> lane(r,q) holds V[out_row=r][local col 4q+m]  (= horiz A-frag!)
//   horizontal: D = A_vreg x B_wgt -> SSIM epilogue on fragments.
// One banded weight fragment W[k-r] serves as B in both passes (band symmetry).
// Weights vanish for k>=26, so clamped staging rows 26..31 contribute zero.

typedef _Float16 f16;
typedef __attribute__((ext_vector_type(4))) _Float16 f16x4;
typedef __attribute__((ext_vector_type(8))) _Float16 f16x8;
typedef __attribute__((ext_vector_type(4))) float f32x4;

constexpr int WIN = 11;
constexpr int H = 512, W = 512, NIMG = 32;
constexpr int OH = H - WIN + 1, OW = W - WIN + 1;  // 502
constexpr int OR_ = 16;      // output rows per block
constexpr int OC = 112;      // output cols per block (7 groups of 16)
constexpr int SC = 128;      // staged cols (8 groups of 16)
constexpr int KP = 36;       // SB k-pitch in f16 (72B row: conflict-free)
constexpr int NSTRIP = 32;   // ceil(502/16)
constexpr int NCB = 5;       // ceil(502/112)
constexpr int NBLK = NIMG * NSTRIP * NCB;  // 5120
constexpr float C1 = 0.009801f;   // (0.01*9.9)^2
constexpr float C2 = 0.088209f;   // (0.03*9.9)^2
constexpr double TOTAL = (double)NIMG * (double)OH * (double)OW;

__device__ constexpr float WGT[WIN] = {
    0.0010285f, 0.0075988f, 0.0360008f, 0.1093607f, 0.2130054f,
    0.2660118f,
    0.2130054f, 0.1093607f, 0.0360008f, 0.0075988f, 0.0010285f};

__global__ __launch_bounds__(256, 4) void ssim_mfma_kernel(const float* __restrict__ P,
                                                           const float* __restrict__ G,
                                                           float* __restrict__ blocksum) {
    __shared__ f16 SB[2][SC][KP];    // staged p,g col-major in k (18432 B)
    __shared__ float wsum[4];

    const int tid = threadIdx.x;
    const int lane = tid & 63;
    const int wid = tid >> 6;
    const int r = lane & 15;         // A row / B col / D col
    const int q = lane >> 4;         // k-group; D rows 4q..4q+3

    const int bid = blockIdx.x;
    const int img = bid / (NSTRIP * NCB);
    const int rem = bid % (NSTRIP * NCB);
    const int strip = rem / NCB;
    const int cb = rem % NCB;
    const int R0 = strip * OR_;
    const int C0 = cb * OC;

    // banded weight fragment: elem e -> k; value W[k - r] (0 outside band).
    // Serves as B for both passes: B[k][j=r] = W[k-j].   [r10/r11-verified mapping]
    f16x8 wfrag;
#pragma unroll
    for (int e = 0; e < 8; ++e) {
        const int k = (e < 4) ? (4 * q + e) : (16 + 4 * q + (e - 4));
        const int d = k - r;
        wfrag[e] = (d >= 0 && d <= 10) ? (f16)WGT[d] : (f16)0.f;
    }

    const float* p = P + (size_t)img * H * W;
    const float* g = G + (size_t)img * H * W;

    // ---- stage rows R0..R0+31 (k 0..31, clamped; k>=26 gets zero weight)
    for (int t = tid; t < 8 * SC; t += 256) {
        const int quad = t >> 7;       // wave-uniform
        const int col = t & 127;
        const int gc = min(C0 + col, W - 1);
        f16x4 cp, cg_;
#pragma unroll
        for (int i = 0; i < 4; ++i) {
            const int gr = min(R0 + 4 * quad + i, H - 1);
            cp[i] = (f16)p[gr * W + gc];
            cg_[i] = (f16)g[gr * W + gc];
        }
        *(f16x4*)&SB[0][col][4 * quad] = cp;
        *(f16x4*)&SB[1][col][4 * quad] = cg_;
    }
    __syncthreads();

    const f32x4 zero = {0.f, 0.f, 0.f, 0.f};

    // ---- vertical MFMA into registers: wave w covers colgroups 2w..2w+2
    // (wave 3 duplicates cg 7; static indices keep vacc in VGPRs)
    f32x4 vacc[3][5];
#pragma unroll
    for (int i = 0; i < 3; ++i) {
        const int cg = min(2 * wid + i, 7);
        const int col = cg * 16 + r;
        const f16* sb0 = &SB[0][col][0];
        const f16* sb1 = &SB[1][col][0];
        const f16x4 p0 = *(const f16x4*)(sb0 + 4 * q);
        const f16x4 p1 = *(const f16x4*)(sb0 + 16 + 4 * q);
        const f16x4 g0 = *(const f16x4*)(sb1 + 4 * q);
        const f16x4 g1 = *(const f16x4*)(sb1 + 16 + 4 * q);
        const f16x8 ap = __builtin_shufflevector(p0, p1, 0, 1, 2, 3, 4, 5, 6, 7);
        const f16x8 ag = __builtin_shufflevector(g0, g1, 0, 1, 2, 3, 4, 5, 6, 7);
        const f16x8 app = ap * ap;
        const f16x8 agg = ag * ag;
        const f16x8 apg = ap * ag;
        vacc[i][0] = __builtin_amdgcn_mfma_f32_16x16x32_f16(ap,  wfrag, zero, 0, 0, 0);
        vacc[i][1] = __builtin_amdgcn_mfma_f32_16x16x32_f16(ag,  wfrag, zero, 0, 0, 0);
        vacc[i][2] = __builtin_amdgcn_mfma_f32_16x16x32_f16(app, wfrag, zero, 0, 0, 0);
        vacc[i][3] = __builtin_amdgcn_mfma_f32_16x16x32_f16(agg, wfrag, zero, 0, 0, 0);
        vacc[i][4] = __builtin_amdgcn_mfma_f32_16x16x32_f16(apg, wfrag, zero, 0, 0, 0);
    }

    // ---- horizontal MFMA + SSIM: wave w covers outgroups 2w, 2w+1 (<7)
    float lsum = 0.f;
#pragma unroll
    for (int j = 0; j < 2; ++j) {
        const int og = 2 * wid + j;
        if (og < 7) {                  // wave-uniform
            f32x4 acc[5];
#pragma unroll
            for (int ch = 0; ch < 5; ++ch) {
                f16x4 lo, hi;
#pragma unroll
                for (int e = 0; e < 4; ++e) {
                    lo[e] = (f16)vacc[j][ch][e];
                    hi[e] = (f16)vacc[j + 1][ch][e];
                }
                const f16x8 afrag = __builtin_shufflevector(lo, hi, 0, 1, 2, 3, 4, 5, 6, 7);
                acc[ch] = __builtin_amdgcn_mfma_f32_16x16x32_f16(afrag, wfrag, zero, 0, 0, 0);
            }
            const int ocol = C0 + og * 16 + r;
#pragma unroll
            for (int m = 0; m < 4; ++m) {
                const int orow = R0 + 4 * q + m;
                const bool ok = (orow < OH) && (ocol < OW);
                const float m1 = acc[0][m], m2 = acc[1][m];
                const float e11 = acc[2][m], e22 = acc[3][m], e12 = acc[4][m];
                const float mu11 = m1 * m1, mu22 = m2 * m2, mu12 = m1 * m2;
                const float s11 = e11 - mu11, s22 = e22 - mu22, s12 = e12 - mu12;
                const float num = (2.f * mu12 + C1) * (2.f * s12 + C2);
                const float den = (mu11 + mu22 + C1) * (s11 + s22 + C2);
                lsum += ok ? __fdividef(num, den) : 0.f;
            }
        }
    }

    // ---- block reduction
#pragma unroll
    for (int off = 32; off > 0; off >>= 1)
        lsum += __shfl_down(lsum, off, 64);
    if (lane == 0) wsum[wid] = lsum;
    __syncthreads();
    if (tid == 0)
        blocksum[bid] = (wsum[0] + wsum[1]) + (wsum[2] + wsum[3]);
}

// one-block reduction of 5120 block sums -> loss scalar
__global__ __launch_bounds__(256) void reduce_kernel(const float* __restrict__ blocksum,
                                                     float* __restrict__ out, int n) {
    const int tid = threadIdx.x;
    float s = 0.f;
    for (int i = tid; i < n; i += 256) s += blocksum[i];
#pragma unroll
    for (int off = 32; off > 0; off >>= 1)
        s += __shfl_down(s, off, 64);
    __shared__ float wsum[4];
    const int wid = tid >> 6, lane = tid & 63;
    if (lane == 0) wsum[wid] = s;
    __syncthreads();
    if (tid == 0) {
        const float total = (wsum[0] + wsum[1]) + (wsum[2] + wsum[3]);
        out[0] = 1.f - total * (float)(1.0 / TOTAL);
    }
}

extern "C" void kernel_launch(void* const* d_in, const int* in_sizes, int n_in,
                              void* d_out, int out_size, void* d_ws, size_t ws_size,
                              hipStream_t stream) {
    const float* P = (const float*)d_in[0];   // predict
    const float* G = (const float*)d_in[1];   // gt
    float* out = (float*)d_out;
    float* blocksum = (float*)d_ws;           // NBLK floats

    ssim_mfma_kernel<<<NBLK, 256, 0, stream>>>(P, G, blocksum);
    reduce_kernel<<<1, 256, 0, stream>>>(blocksum, out, NBLK);
}